// Round 1
// baseline (297.733 us; speedup 1.0000x reference)
//
#include <hip/hip_runtime.h>

#define NC 16384        // num classes == batch
#define FD 128          // feature dim
#define LAMBDA 0.005f
#define GB_PER_MAT 128  // gram blocks per matrix (128 rows each)
#define DIAG_BLOCKS 256

__device__ __forceinline__ float wave_sum(float v) {
#pragma unroll
  for (int m = 32; m > 0; m >>= 1) v += __shfl_xor(v, m, 64);
  return v;
}

// --- 1. segment sum: sums[label] += z[i], counts[label]++ --------------------
__global__ __launch_bounds__(256) void seg_kernel(
    const float* __restrict__ z, const int* __restrict__ labels,
    float* __restrict__ sums, unsigned int* __restrict__ counts) {
  int t = threadIdx.x;
  int i = blockIdx.x * 8 + (t >> 5);   // 8 samples / block
  int d0 = (t & 31) * 4;               // 32 lanes x float4 = 128 dims
  int lab = labels[i];
  const float4 v = *(const float4*)&z[(size_t)i * FD + d0];
  float* dst = &sums[(size_t)lab * FD + d0];
  unsafeAtomicAdd(dst + 0, v.x);
  unsafeAtomicAdd(dst + 1, v.y);
  unsafeAtomicAdd(dst + 2, v.z);
  unsafeAtomicAdd(dst + 3, v.w);
  if ((t & 31) == 0) atomicAdd(&counts[lab], 1u);
}

// --- 2. fused normalize: rows [0,NC) -> Zn from z; rows [NC,2NC) -> Cn over centers (in-place) ---
__global__ __launch_bounds__(256) void norm_kernel(
    const float* __restrict__ z, float* centers /* sums in, Cn out, aliased */,
    const unsigned int* __restrict__ counts, float* __restrict__ zn) {
  int wave = threadIdx.x >> 6;
  int lane = threadIdx.x & 63;
  int row = blockIdx.x * 4 + wave;     // [0, 2*NC)
  float2 v;
  if (row < NC) {
    v = *(const float2*)&z[(size_t)row * FD + lane * 2];
  } else {
    int r = row - NC;
    float cnt = (float)counts[r];
    float inv = cnt > 0.f ? 1.f / cnt : 0.f;
    float2 s = *(const float2*)&centers[(size_t)r * FD + lane * 2];
    v.x = s.x * inv;
    v.y = s.y * inv;
  }
  float ss = wave_sum(v.x * v.x + v.y * v.y);
  float scale = 1.0f / fmaxf(sqrtf(ss), 1e-12f);
  v.x *= scale;
  v.y *= scale;
  if (row < NC) {
    *(float2*)&zn[(size_t)row * FD + lane * 2] = v;
  } else {
    *(float2*)&centers[(size_t)(row - NC) * FD + lane * 2] = v;
  }
}

// --- 3. Gram matrices G = A^T A (128x128, K=16384) + diag dots ---------------
// blocks [0,128): G_z chunks; [128,256): G_c chunks; [256,512): diag
__global__ __launch_bounds__(256) void gram_diag_kernel(
    const float* __restrict__ zn, const float* __restrict__ cn,
    float* __restrict__ gz, float* __restrict__ gc, float* __restrict__ scal) {
  __shared__ float lds[64 * FD];  // 32 KB tile: 64 rows x 128
  int b = blockIdx.x;
  int t = threadIdx.x;

  if (b < 2 * GB_PER_MAT) {
    const float* A = (b < GB_PER_MAT) ? zn : cn;
    float* G = (b < GB_PER_MAT) ? gz : gc;
    int row0 = (b % GB_PER_MAT) * (NC / GB_PER_MAT);  // 128 rows per block
    int d = t >> 1;             // output row 0..127
    int e0 = (t & 1) * 64;      // output col half
    float4 acc[16];
#pragma unroll
    for (int k = 0; k < 16; ++k) acc[k] = make_float4(0.f, 0.f, 0.f, 0.f);

    for (int tile = 0; tile < 2; ++tile) {  // 2 x 64-row tiles
      const float4* src = (const float4*)&A[(size_t)(row0 + tile * 64) * FD];
      float4* dst = (float4*)lds;
#pragma unroll
      for (int k = 0; k < 8; ++k) dst[k * 256 + t] = src[k * 256 + t];
      __syncthreads();
#pragma unroll 4
      for (int r = 0; r < 64; ++r) {
        float a = lds[r * FD + d];
        const float4* row4 = (const float4*)&lds[r * FD + e0];
#pragma unroll
        for (int k = 0; k < 16; ++k) {
          float4 v = row4[k];
          acc[k].x += a * v.x;
          acc[k].y += a * v.y;
          acc[k].z += a * v.z;
          acc[k].w += a * v.w;
        }
      }
      __syncthreads();
    }
    float* Grow = &G[(size_t)d * FD + e0];
#pragma unroll
    for (int k = 0; k < 16; ++k) {
      unsafeAtomicAdd(Grow + k * 4 + 0, acc[k].x);
      unsafeAtomicAdd(Grow + k * 4 + 1, acc[k].y);
      unsafeAtomicAdd(Grow + k * 4 + 2, acc[k].z);
      unsafeAtomicAdd(Grow + k * 4 + 3, acc[k].w);
    }
  } else {
    // diag: raw_i = zn_i . cn_i ; accumulate s1=sum raw, s2=sum raw^2
    int db = b - 2 * GB_PER_MAT;  // 0..255
    int wave = t >> 6, lane = t & 63;
    int gw = db * 4 + wave;       // 0..1023
    float s1 = 0.f, s2 = 0.f;
#pragma unroll
    for (int j = 0; j < NC / 1024; ++j) {  // 16 rows per wave
      int r = gw + j * 1024;
      const float2 a = *(const float2*)&zn[(size_t)r * FD + lane * 2];
      const float2 c = *(const float2*)&cn[(size_t)r * FD + lane * 2];
      float dot = wave_sum(a.x * c.x + a.y * c.y);
      if (lane == 0) {
        s1 += dot;
        s2 += dot * dot;
      }
    }
    if (lane == 0) {
      lds[wave * 2] = s1;
      lds[wave * 2 + 1] = s2;
    }
    __syncthreads();
    if (t == 0) {
      unsafeAtomicAdd(&scal[0], lds[0] + lds[2] + lds[4] + lds[6]);
      unsafeAtomicAdd(&scal[1], lds[1] + lds[3] + lds[5] + lds[7]);
    }
  }
}

// --- 4. combine: S = <G_z, G_c>_F ; loss = inv + lambda*red ------------------
__global__ __launch_bounds__(256) void combine_kernel(
    const float* __restrict__ gz, const float* __restrict__ gc,
    const float* __restrict__ scal, float* __restrict__ out) {
  __shared__ float red[8];
  int t = threadIdx.x;
  float S = 0.f;
#pragma unroll 8
  for (int k = 0; k < 64; ++k) {
    int idx = k * 256 + t;
    S += gz[idx] * gc[idx];
  }
  S = wave_sum(S);
  int wave = t >> 6, lane = t & 63;
  if (lane == 0) red[wave] = S;
  __syncthreads();
  if (t == 0) {
    double Sall = (double)red[0] + red[1] + red[2] + red[3];
    double s1 = (double)scal[0];
    double s2 = (double)scal[1];
    double B = (double)NC;
    double inv_loss = s2 / (B * B) - 2.0 * s1 / B + (double)NC;
    double red_loss = (Sall - s2) / (B * B);
    out[0] = (float)(inv_loss + (double)LAMBDA * red_loss);
  }
}

extern "C" void kernel_launch(void* const* d_in, const int* in_sizes, int n_in,
                              void* d_out, int out_size, void* d_ws, size_t ws_size,
                              hipStream_t stream) {
  const float* z = (const float*)d_in[0];
  const int* labels = (const int*)d_in[1];
  float* out = (float*)d_out;
  float* ws = (float*)d_ws;

  // ws layout (floats):
  float* sums = ws;                                   // NC*FD (becomes Cn in-place)
  unsigned int* counts = (unsigned int*)(ws + (size_t)NC * FD);  // NC uints
  float* gz = ws + (size_t)NC * FD + NC;              // FD*FD
  float* gc = gz + FD * FD;                           // FD*FD
  float* scal = gc + FD * FD;                         // 2 floats (+pad)
  size_t zero_floats = (size_t)NC * FD + NC + 2 * FD * FD + 8;
  size_t zn_off = (zero_floats + 511) & ~(size_t)511;
  float* zn = ws + zn_off;                            // NC*FD

  hipMemsetAsync(ws, 0, zero_floats * sizeof(float), stream);
  seg_kernel<<<NC / 8, 256, 0, stream>>>(z, labels, sums, counts);
  norm_kernel<<<(2 * NC) / 4, 256, 0, stream>>>(z, sums, counts, zn);
  gram_diag_kernel<<<2 * GB_PER_MAT + DIAG_BLOCKS, 256, 0, stream>>>(zn, sums, gz, gc, scal);
  combine_kernel<<<1, 256, 0, stream>>>(gz, gc, scal, out);
}

// Round 2
// 209.913 us; speedup vs baseline: 1.4184x; 1.4184x over previous
//
#include <hip/hip_runtime.h>

#define NC 16384        // num classes == batch
#define FD 128          // feature dim
#define LAMBDA 0.005f
#define KB 128          // K-rows per gram block

__device__ __forceinline__ float wave_sum(float v) {
#pragma unroll
  for (int m = 32; m > 0; m >>= 1) v += __shfl_xor(v, m, 64);
  return v;
}

// --- 1. segment sum: sums[label] += z[i], counts[label]++ --------------------
__global__ __launch_bounds__(256) void seg_kernel(
    const float* __restrict__ z, const int* __restrict__ labels,
    float* __restrict__ sums, unsigned int* __restrict__ counts) {
  int t = threadIdx.x;
  int i = blockIdx.x * 8 + (t >> 5);   // 8 samples / block
  int d0 = (t & 31) * 4;               // 32 lanes x float4 = 128 dims
  int lab = labels[i];
  const float4 v = *(const float4*)&z[(size_t)i * FD + d0];
  float* dst = &sums[(size_t)lab * FD + d0];
  unsafeAtomicAdd(dst + 0, v.x);
  unsafeAtomicAdd(dst + 1, v.y);
  unsafeAtomicAdd(dst + 2, v.z);
  unsafeAtomicAdd(dst + 3, v.w);
  if ((t & 31) == 0) atomicAdd(&counts[lab], 1u);
}

// --- 2. fused normalize + diag: zn = norm(z); cn = norm(sums/counts) in-place
//        over sums; s1 += zn_i.cn_i ; s2 += (zn_i.cn_i)^2 ----------------------
__global__ __launch_bounds__(256) void normdiag_kernel(
    const float* __restrict__ z, float* __restrict__ sums /* in: sums, out: cn */,
    const unsigned int* __restrict__ counts,
    float* __restrict__ zn, float* __restrict__ scal) {
  __shared__ float red[8];
  int t = threadIdx.x, wave = t >> 6, lane = t & 63;
  float s1 = 0.f, s2 = 0.f;
#pragma unroll
  for (int j = 0; j < 4; ++j) {
    int row = blockIdx.x * 16 + wave * 4 + j;
    // normalize z row
    float2 a = *(const float2*)&z[(size_t)row * FD + lane * 2];
    float sa = wave_sum(a.x * a.x + a.y * a.y);
    float ia = 1.0f / fmaxf(sqrtf(sa), 1e-12f);
    a.x *= ia; a.y *= ia;
    *(float2*)&zn[(size_t)row * FD + lane * 2] = a;
    // normalize center row (sums/count), in place
    unsigned int cnt = counts[row];
    float ic = cnt ? 1.0f / (float)cnt : 0.0f;
    float2 c = *(const float2*)&sums[(size_t)row * FD + lane * 2];
    c.x *= ic; c.y *= ic;
    float sc = wave_sum(c.x * c.x + c.y * c.y);
    float in = 1.0f / fmaxf(sqrtf(sc), 1e-12f);
    c.x *= in; c.y *= in;
    *(float2*)&sums[(size_t)row * FD + lane * 2] = c;
    // diag dot
    float d = wave_sum(a.x * c.x + a.y * c.y);
    s1 += d; s2 += d * d;
  }
  if (lane == 0) { red[wave * 2] = s1; red[wave * 2 + 1] = s2; }
  __syncthreads();
  if (t == 0) {
    unsafeAtomicAdd(&scal[0], red[0] + red[2] + red[4] + red[6]);
    unsafeAtomicAdd(&scal[1], red[1] + red[3] + red[5] + red[7]);
  }
}

// --- 3. Gram: G = A^T A (128x128, K=16384), KB rows per block ----------------
// block b: matrix m = b&1 (0->zn/gz, 1->cn/gc), K-chunk = b>>1.
// 512 threads; thread patch = 4 rows (d0=ty*4) x 8 cols (e0=tx*8).
__global__ __launch_bounds__(512) void gram_kernel(
    const float* __restrict__ zn, const float* __restrict__ cn,
    float* __restrict__ gz, float* __restrict__ gc) {
  __shared__ float tile[KB * FD];  // 64 KB
  int t = threadIdx.x;
  int b = blockIdx.x;
  const float* A = (b & 1) ? cn : zn;
  float* G = (b & 1) ? gc : gz;
  int chunk = b >> 1;

  // stage KB x FD tile, coalesced float4
  {
    const float4* src = (const float4*)&A[(size_t)chunk * KB * FD];
    float4* dst = (float4*)tile;
#pragma unroll
    for (int k = 0; k < (KB * FD / 4) / 512; ++k)  // 8 iters
      dst[k * 512 + t] = src[k * 512 + t];
  }
  __syncthreads();

  int tx = t & 15;        // 16 -> e0
  int ty = t >> 4;        // 32 -> d0
  float4 acc[4][2];
#pragma unroll
  for (int i = 0; i < 4; ++i) {
    acc[i][0] = make_float4(0.f, 0.f, 0.f, 0.f);
    acc[i][1] = make_float4(0.f, 0.f, 0.f, 0.f);
  }

  const float4* t4 = (const float4*)tile;
#pragma unroll 2
  for (int r = 0; r < KB; ++r) {
    float4 a4 = t4[r * 32 + ty];            // cols d0..d0+3 (broadcast, no conflict)
    float4 b0 = t4[r * 32 + tx * 2];        // cols e0..e0+3
    float4 b1 = t4[r * 32 + tx * 2 + 1];    // cols e0+4..e0+7
    float av[4] = {a4.x, a4.y, a4.z, a4.w};
#pragma unroll
    for (int i = 0; i < 4; ++i) {
      acc[i][0].x += av[i] * b0.x;
      acc[i][0].y += av[i] * b0.y;
      acc[i][0].z += av[i] * b0.z;
      acc[i][0].w += av[i] * b0.w;
      acc[i][1].x += av[i] * b1.x;
      acc[i][1].y += av[i] * b1.y;
      acc[i][1].z += av[i] * b1.z;
      acc[i][1].w += av[i] * b1.w;
    }
  }

  int d0 = ty * 4, e0 = tx * 8;
#pragma unroll
  for (int i = 0; i < 4; ++i) {
#pragma unroll
    for (int jj = 0; jj < 2; ++jj) {
      float* dst = &G[(size_t)(d0 + i) * FD + e0 + jj * 4];
      float4 v = acc[i][jj];
      unsafeAtomicAdd(dst + 0, v.x);
      unsafeAtomicAdd(dst + 1, v.y);
      unsafeAtomicAdd(dst + 2, v.z);
      unsafeAtomicAdd(dst + 3, v.w);
    }
  }
}

// --- 4. combine: S = <G_z, G_c>_F ; loss = inv + lambda*red ------------------
__global__ __launch_bounds__(256) void combine_kernel(
    const float* __restrict__ gz, const float* __restrict__ gc,
    const float* __restrict__ scal, float* __restrict__ out) {
  __shared__ float red[4];
  int t = threadIdx.x;
  float S = 0.f;
#pragma unroll 8
  for (int k = 0; k < 64; ++k) {
    int idx = k * 256 + t;
    S += gz[idx] * gc[idx];
  }
  S = wave_sum(S);
  int wave = t >> 6, lane = t & 63;
  if (lane == 0) red[wave] = S;
  __syncthreads();
  if (t == 0) {
    double Sall = (double)red[0] + red[1] + red[2] + red[3];
    double s1 = (double)scal[0];
    double s2 = (double)scal[1];
    double B = (double)NC;
    double inv_loss = s2 / (B * B) - 2.0 * s1 / B + (double)NC;
    double red_loss = (Sall - s2) / (B * B);
    out[0] = (float)(inv_loss + (double)LAMBDA * red_loss);
  }
}

extern "C" void kernel_launch(void* const* d_in, const int* in_sizes, int n_in,
                              void* d_out, int out_size, void* d_ws, size_t ws_size,
                              hipStream_t stream) {
  const float* z = (const float*)d_in[0];
  const int* labels = (const int*)d_in[1];
  float* out = (float*)d_out;
  float* ws = (float*)d_ws;

  // ws layout (floats): [sums NC*FD][counts NC][gz FD*FD][gc FD*FD][scal 8][align][zn NC*FD]
  float* sums = ws;
  unsigned int* counts = (unsigned int*)(ws + (size_t)NC * FD);
  float* gz = ws + (size_t)NC * FD + NC;
  float* gc = gz + FD * FD;
  float* scal = gc + FD * FD;
  size_t zero_floats = (size_t)NC * FD + NC + 2 * FD * FD + 8;
  size_t zn_off = (zero_floats + 511) & ~(size_t)511;
  float* zn = ws + zn_off;

  hipMemsetAsync(ws, 0, zero_floats * sizeof(float), stream);
  seg_kernel<<<NC / 8, 256, 0, stream>>>(z, labels, sums, counts);
  normdiag_kernel<<<NC / 16, 256, 0, stream>>>(z, sums, counts, zn, scal);
  gram_kernel<<<2 * (NC / KB), 512, 0, stream>>>(zn, sums, gz, gc);
  combine_kernel<<<1, 256, 0, stream>>>(gz, gc, scal, out);
}

// Round 3
// 95.809 us; speedup vs baseline: 3.1076x; 2.1910x over previous
//
#include <hip/hip_runtime.h>

#define NC 16384        // num classes == batch
#define FD 128          // feature dim
#define LAMBDA 0.005f
#define CB 64           // classes per center block
#define CHUNK 128       // K rows per gram block
#define STAGE 64        // rows per LDS stage
#define NPB 128         // gram partial blocks per matrix (NC/CHUNK)

__device__ __forceinline__ float wave_sum(float v) {
#pragma unroll
  for (int m = 32; m > 0; m >>= 1) v += __shfl_xor(v, m, 64);
  return v;
}

// --- 1. centers: per-class mean + L2 normalize -> cn (no global atomics) -----
// Block b owns classes [b*CB, b*CB+CB). Scan all labels, gather matching rows.
__global__ __launch_bounds__(256) void center_kernel(
    const float* __restrict__ z, const int* __restrict__ labels,
    float* __restrict__ cn) {
  __shared__ float sums[CB * FD];   // 32 KB
  __shared__ int list[1024];
  __shared__ int counts[CB];
  __shared__ int nlist;
  int t = threadIdx.x, wave = t >> 6, lane = t & 63;
  int base = blockIdx.x * CB;

  for (int k = t; k < CB * FD; k += 256) sums[k] = 0.f;
  if (t < CB) counts[t] = 0;
  if (t == 0) nlist = 0;
  __syncthreads();

  // scan labels (64 KB, L2/L1 resident across blocks)
#pragma unroll 4
  for (int k = 0; k < NC / 256; ++k) {
    int j = k * 256 + t;
    int lab = labels[j];
    unsigned loc = (unsigned)(lab - base);
    if (loc < CB) {
      int pos = atomicAdd(&nlist, 1);             // LDS atomic
      if (pos < 1024) list[pos] = (j << 6) | (int)loc;
      atomicAdd(&counts[loc], 1);                 // LDS atomic
    }
  }
  __syncthreads();

  // accumulate: wave w owns local classes [w*16, w*16+16) -> no races
  int n = nlist > 1024 ? 1024 : nlist;
  for (int e = 0; e < n; ++e) {
    int ent = list[e];
    int loc = ent & 63;
    if ((loc >> 4) != wave) continue;
    int i = ent >> 6;
    float2 v = *(const float2*)&z[(size_t)i * FD + lane * 2];
    float2* s = (float2*)&sums[loc * FD + lane * 2];
    float2 cur = *s;
    cur.x += v.x; cur.y += v.y;
    *s = cur;
  }
  __syncthreads();

  // divide by count, L2-normalize, write out (16 rows per wave)
#pragma unroll
  for (int j = 0; j < 16; ++j) {
    int row = wave * 16 + j;
    int cnt = counts[row];
    float inv = cnt > 0 ? 1.0f / (float)cnt : 0.0f;
    float2 v = *(const float2*)&sums[row * FD + lane * 2];
    v.x *= inv; v.y *= inv;
    float ss = wave_sum(v.x * v.x + v.y * v.y);
    float sc = 1.0f / fmaxf(sqrtf(ss), 1e-12f);
    v.x *= sc; v.y *= sc;
    *(float2*)&cn[(size_t)(base + row) * FD + lane * 2] = v;
  }
}

// --- 2. diag: s1 += zn_i.cn_i, s2 += (.)^2 ; zn computed on the fly ----------
__global__ __launch_bounds__(256) void diag_kernel(
    const float* __restrict__ z, const float* __restrict__ cn,
    float* __restrict__ scal) {
  __shared__ float red[8];
  int t = threadIdx.x, wave = t >> 6, lane = t & 63;
  float s1 = 0.f, s2 = 0.f;
#pragma unroll
  for (int j = 0; j < 16; ++j) {
    int row = blockIdx.x * 64 + wave * 16 + j;
    float2 a = *(const float2*)&z[(size_t)row * FD + lane * 2];
    float ss = wave_sum(a.x * a.x + a.y * a.y);
    float ia = 1.0f / fmaxf(sqrtf(ss), 1e-12f);
    float2 c = *(const float2*)&cn[(size_t)row * FD + lane * 2];
    float d = wave_sum(a.x * c.x + a.y * c.y) * ia;
    s1 += d; s2 += d * d;
  }
  if (lane == 0) { red[wave * 2] = s1; red[wave * 2 + 1] = s2; }
  __syncthreads();
  if (t == 0) {
    unsafeAtomicAdd(&scal[0], red[0] + red[2] + red[4] + red[6]);
    unsafeAtomicAdd(&scal[1], red[1] + red[3] + red[5] + red[7]);
  }
}

// --- 3. gram partials: block b -> matrix m=b&1, K-chunk b>>1 (128 rows) ------
// 8x8 register tile per thread, one-row prefetch, z normalized in LDS.
__global__ __launch_bounds__(256) void gram_kernel(
    const float* __restrict__ z, const float* __restrict__ cn,
    float* __restrict__ partials) {
  __shared__ float tile[STAGE * FD];  // 32 KB
  int t = threadIdx.x, wave = t >> 6, lane = t & 63;
  int b = blockIdx.x;
  int m = b & 1;
  int chunk = b >> 1;
  const float* A = m ? cn : z;
  int tx = t & 15, ty = t >> 4;

  float4 acc[8][2];
#pragma unroll
  for (int i = 0; i < 8; ++i) {
    acc[i][0] = make_float4(0.f, 0.f, 0.f, 0.f);
    acc[i][1] = make_float4(0.f, 0.f, 0.f, 0.f);
  }
  const float4* t4 = (const float4*)tile;

  for (int s = 0; s < CHUNK / STAGE; ++s) {
    {  // stage 64x128 floats, coalesced float4
      const float4* src = (const float4*)&A[(size_t)(chunk * CHUNK + s * STAGE) * FD];
      float4* dst = (float4*)tile;
#pragma unroll
      for (int k = 0; k < (STAGE * FD / 4) / 256; ++k)
        dst[k * 256 + t] = src[k * 256 + t];
    }
    __syncthreads();
    if (m == 0) {  // normalize z rows in LDS (16 rows per wave)
      float2* t2 = (float2*)tile;
#pragma unroll
      for (int j = 0; j < 16; ++j) {
        int row = wave * 16 + j;
        float2 v = t2[row * 64 + lane];
        float ss = wave_sum(v.x * v.x + v.y * v.y);
        float sc = 1.0f / fmaxf(sqrtf(ss), 1e-12f);
        v.x *= sc; v.y *= sc;
        t2[row * 64 + lane] = v;
      }
      __syncthreads();
    }
    // FMA loop with one-row register prefetch
    float4 a0 = t4[ty * 2], a1 = t4[ty * 2 + 1];
    float4 b0 = t4[tx * 2], b1 = t4[tx * 2 + 1];
    for (int r = 0; r < STAGE; ++r) {
      int rn = (r + 1) & (STAGE - 1);
      float4 na0 = t4[rn * 32 + ty * 2];
      float4 na1 = t4[rn * 32 + ty * 2 + 1];
      float4 nb0 = t4[rn * 32 + tx * 2];
      float4 nb1 = t4[rn * 32 + tx * 2 + 1];
      float av[8] = {a0.x, a0.y, a0.z, a0.w, a1.x, a1.y, a1.z, a1.w};
#pragma unroll
      for (int i = 0; i < 8; ++i) {
        float a = av[i];
        acc[i][0].x += a * b0.x;
        acc[i][0].y += a * b0.y;
        acc[i][0].z += a * b0.z;
        acc[i][0].w += a * b0.w;
        acc[i][1].x += a * b1.x;
        acc[i][1].y += a * b1.y;
        acc[i][1].z += a * b1.z;
        acc[i][1].w += a * b1.w;
      }
      a0 = na0; a1 = na1; b0 = nb0; b1 = nb1;
    }
    __syncthreads();
  }

  // plain coalesced partial store (no atomics)
  int d0 = ty * 8, e0 = tx * 8;
  float* P = &partials[(size_t)b * (FD * FD)];
#pragma unroll
  for (int i = 0; i < 8; ++i) {
    *(float4*)&P[(d0 + i) * FD + e0] = acc[i][0];
    *(float4*)&P[(d0 + i) * FD + e0 + 4] = acc[i][1];
  }
}

// --- 4. reduce partials + Frobenius product ----------------------------------
__global__ __launch_bounds__(256) void reduce_kernel(
    const float* __restrict__ partials, float* __restrict__ scal) {
  __shared__ float lz[4][64], lc[4][64];
  int t = threadIdx.x, wave = t >> 6, lane = t & 63;
  int e = blockIdx.x * 64 + lane;
  float sz = 0.f, sc = 0.f;
#pragma unroll 4
  for (int k = 0; k < NPB / 4; ++k) {
    int c = wave * (NPB / 4) + k;
    sz += partials[(size_t)(2 * c) * (FD * FD) + e];
    sc += partials[(size_t)(2 * c + 1) * (FD * FD) + e];
  }
  lz[wave][lane] = sz;
  lc[wave][lane] = sc;
  __syncthreads();
  if (wave == 0) {
    float tz = lz[0][lane] + lz[1][lane] + lz[2][lane] + lz[3][lane];
    float tc = lc[0][lane] + lc[1][lane] + lc[2][lane] + lc[3][lane];
    float S = wave_sum(tz * tc);
    if (lane == 0) unsafeAtomicAdd(&scal[2], S);
  }
}

// --- 5. final loss ------------------------------------------------------------
__global__ void final_kernel(const float* __restrict__ scal, float* __restrict__ out) {
  double s1 = scal[0], s2 = scal[1], S = scal[2];
  double B = (double)NC;
  double inv_loss = s2 / (B * B) - 2.0 * s1 / B + (double)NC;
  double red_loss = (S - s2) / (B * B);
  out[0] = (float)(inv_loss + (double)LAMBDA * red_loss);
}

extern "C" void kernel_launch(void* const* d_in, const int* in_sizes, int n_in,
                              void* d_out, int out_size, void* d_ws, size_t ws_size,
                              hipStream_t stream) {
  const float* z = (const float*)d_in[0];
  const int* labels = (const int*)d_in[1];
  float* out = (float*)d_out;
  float* ws = (float*)d_ws;

  // ws layout (floats): [cn NC*FD][scal 16][partials 2*NPB*FD*FD]  ~25.2 MB
  float* cn = ws;
  float* scal = ws + (size_t)NC * FD;
  float* partials = scal + 16;

  hipMemsetAsync(scal, 0, 16 * sizeof(float), stream);
  center_kernel<<<NC / CB, 256, 0, stream>>>(z, labels, cn);
  diag_kernel<<<NC / 64, 256, 0, stream>>>(z, cn, scal);
  gram_kernel<<<2 * NPB, 256, 0, stream>>>(z, cn, partials);
  reduce_kernel<<<FD * FD / 64, 256, 0, stream>>>(partials, scal);
  final_kernel<<<1, 1, 0, stream>>>(scal, out);
}

// Round 4
// 83.217 us; speedup vs baseline: 3.5778x; 1.1513x over previous
//
#include <hip/hip_runtime.h>

#define NC 16384        // num classes == batch
#define FD 128          // feature dim
#define LAMBDA 0.005f
#define CB 64           // classes per center block
#define CHUNK 128       // K rows per gram block
#define STAGE 64        // rows per LDS stage
#define NPB 128         // gram partial blocks per matrix (NC/CHUNK)
#define LISTCAP 2048

__device__ __forceinline__ float wave_sum(float v) {
#pragma unroll
  for (int m = 32; m > 0; m >>= 1) v += __shfl_xor(v, m, 64);
  return v;
}

// --- 1. centers + diag: per-class mean + L2 normalize -> cn; also
//        s1/s2 diag partials for rows [b*CB, b*CB+CB) (plain store, no atomics)
__global__ __launch_bounds__(256) void center_kernel(
    const float* __restrict__ z, const int* __restrict__ labels,
    float* __restrict__ cn, float2* __restrict__ dpart) {
  __shared__ float sums[CB * FD];   // 32 KB
  __shared__ int list[LISTCAP];     // 8 KB
  __shared__ int counts[CB];
  __shared__ int nlist;
  __shared__ float red[8];
  int t = threadIdx.x, wave = t >> 6, lane = t & 63;
  int base = blockIdx.x * CB;

  for (int k = t; k < CB * FD; k += 256) sums[k] = 0.f;
  if (t < CB) counts[t] = 0;
  if (t == 0) nlist = 0;
  __syncthreads();

  // scan labels (64 KB, L1/L2-resident across blocks)
#pragma unroll 4
  for (int k = 0; k < NC / 256; ++k) {
    int j = k * 256 + t;
    int lab = labels[j];
    unsigned loc = (unsigned)(lab - base);
    if (loc < CB) {
      int pos = atomicAdd(&nlist, 1);              // LDS atomic
      if (pos < LISTCAP) list[pos] = (j << 6) | (int)loc;
      atomicAdd(&counts[loc], 1);                  // LDS atomic
    }
  }
  __syncthreads();

  // accumulate: 8 independent 32-lane groups, fire-and-forget LDS f32 atomics
  int n = nlist > LISTCAP ? LISTCAP : nlist;
  int g = t >> 5;          // 0..7
  int sl = t & 31;         // 32 lanes x float4 = 128 dims
  for (int e = g; e < n; e += 8) {
    int ent = list[e];
    int loc = ent & 63;
    int i = ent >> 6;
    const float4 v = *(const float4*)&z[(size_t)i * FD + sl * 4];
    float* s = &sums[loc * FD + sl * 4];
    atomicAdd(s + 0, v.x);   // ds_add_f32, no return -> pipelines
    atomicAdd(s + 1, v.y);
    atomicAdd(s + 2, v.z);
    atomicAdd(s + 3, v.w);
  }
  __syncthreads();

  // divide, normalize, write cn; fused diag (z rows are contiguous here)
  float s1 = 0.f, s2 = 0.f;
#pragma unroll
  for (int j = 0; j < 16; ++j) {
    int row = wave * 16 + j;
    int gr = base + row;
    int cnt = counts[row];
    float inv = cnt > 0 ? 1.0f / (float)cnt : 0.0f;
    float2 c = *(const float2*)&sums[row * FD + lane * 2];
    c.x *= inv; c.y *= inv;
    float sc = wave_sum(c.x * c.x + c.y * c.y);
    float ic = 1.0f / fmaxf(sqrtf(sc), 1e-12f);
    c.x *= ic; c.y *= ic;
    *(float2*)&cn[(size_t)gr * FD + lane * 2] = c;
    float2 a = *(const float2*)&z[(size_t)gr * FD + lane * 2];
    float na = wave_sum(a.x * a.x + a.y * a.y);
    float dd = wave_sum(a.x * c.x + a.y * c.y);
    float d = dd * (1.0f / fmaxf(sqrtf(na), 1e-12f));
    s1 += d; s2 += d * d;
  }
  if (lane == 0) { red[wave * 2] = s1; red[wave * 2 + 1] = s2; }
  __syncthreads();
  if (t == 0) {
    dpart[blockIdx.x] = make_float2(red[0] + red[2] + red[4] + red[6],
                                    red[1] + red[3] + red[5] + red[7]);
  }
}

// --- 2. gram partials: block b -> matrix m=b&1, K-chunk b>>1 (128 rows) ------
__global__ __launch_bounds__(256) void gram_kernel(
    const float* __restrict__ z, const float* __restrict__ cn,
    float* __restrict__ partials) {
  __shared__ float tile[STAGE * FD];  // 32 KB
  int t = threadIdx.x, wave = t >> 6, lane = t & 63;
  int b = blockIdx.x;
  int m = b & 1;
  int chunk = b >> 1;
  const float* A = m ? cn : z;
  int tx = t & 15, ty = t >> 4;

  float4 acc[8][2];
#pragma unroll
  for (int i = 0; i < 8; ++i) {
    acc[i][0] = make_float4(0.f, 0.f, 0.f, 0.f);
    acc[i][1] = make_float4(0.f, 0.f, 0.f, 0.f);
  }
  const float4* t4 = (const float4*)tile;

  for (int s = 0; s < CHUNK / STAGE; ++s) {
    {  // stage 64x128 floats, coalesced float4
      const float4* src = (const float4*)&A[(size_t)(chunk * CHUNK + s * STAGE) * FD];
      float4* dst = (float4*)tile;
#pragma unroll
      for (int k = 0; k < (STAGE * FD / 4) / 256; ++k)
        dst[k * 256 + t] = src[k * 256 + t];
    }
    __syncthreads();
    if (m == 0) {  // normalize z rows in LDS (16 rows per wave)
      float2* t2 = (float2*)tile;
#pragma unroll
      for (int j = 0; j < 16; ++j) {
        int row = wave * 16 + j;
        float2 v = t2[row * 64 + lane];
        float ss = wave_sum(v.x * v.x + v.y * v.y);
        float sc = 1.0f / fmaxf(sqrtf(ss), 1e-12f);
        v.x *= sc; v.y *= sc;
        t2[row * 64 + lane] = v;
      }
      __syncthreads();
    }
    // FMA loop with one-row register prefetch
    float4 a0 = t4[ty * 2], a1 = t4[ty * 2 + 1];
    float4 b0 = t4[tx * 2], b1 = t4[tx * 2 + 1];
    for (int r = 0; r < STAGE; ++r) {
      int rn = (r + 1) & (STAGE - 1);
      float4 na0 = t4[rn * 32 + ty * 2];
      float4 na1 = t4[rn * 32 + ty * 2 + 1];
      float4 nb0 = t4[rn * 32 + tx * 2];
      float4 nb1 = t4[rn * 32 + tx * 2 + 1];
      float av[8] = {a0.x, a0.y, a0.z, a0.w, a1.x, a1.y, a1.z, a1.w};
#pragma unroll
      for (int i = 0; i < 8; ++i) {
        float a = av[i];
        acc[i][0].x += a * b0.x;
        acc[i][0].y += a * b0.y;
        acc[i][0].z += a * b0.z;
        acc[i][0].w += a * b0.w;
        acc[i][1].x += a * b1.x;
        acc[i][1].y += a * b1.y;
        acc[i][1].z += a * b1.z;
        acc[i][1].w += a * b1.w;
      }
      a0 = na0; a1 = na1; b0 = nb0; b1 = nb1;
    }
    __syncthreads();
  }

  // plain coalesced partial store (no atomics)
  int d0 = ty * 8, e0 = tx * 8;
  float* P = &partials[(size_t)b * (FD * FD)];
#pragma unroll
  for (int i = 0; i < 8; ++i) {
    *(float4*)&P[(d0 + i) * FD + e0] = acc[i][0];
    *(float4*)&P[(d0 + i) * FD + e0 + 4] = acc[i][1];
  }
}

// --- 3. reduce partials -> per-block Frobenius partial (plain store) ---------
__global__ __launch_bounds__(256) void reduce_kernel(
    const float* __restrict__ partials, float* __restrict__ spart) {
  __shared__ float lz[4][64], lc[4][64];
  int t = threadIdx.x, wave = t >> 6, lane = t & 63;
  int e = blockIdx.x * 64 + lane;
  float sz = 0.f, sc = 0.f;
#pragma unroll 4
  for (int k = 0; k < NPB / 4; ++k) {
    int c = wave * (NPB / 4) + k;
    sz += partials[(size_t)(2 * c) * (FD * FD) + e];
    sc += partials[(size_t)(2 * c + 1) * (FD * FD) + e];
  }
  lz[wave][lane] = sz;
  lc[wave][lane] = sc;
  __syncthreads();
  if (wave == 0) {
    float tz = lz[0][lane] + lz[1][lane] + lz[2][lane] + lz[3][lane];
    float tc = lc[0][lane] + lc[1][lane] + lc[2][lane] + lc[3][lane];
    float S = wave_sum(tz * tc);
    if (lane == 0) spart[blockIdx.x] = S;
  }
}

// --- 4. final: sum 256 dpart + 256 spart, compose loss -----------------------
__global__ __launch_bounds__(256) void final_kernel(
    const float2* __restrict__ dpart, const float* __restrict__ spart,
    float* __restrict__ out) {
  __shared__ float r[3][4];
  int t = threadIdx.x, wave = t >> 6, lane = t & 63;
  float2 d = dpart[t];
  float s = spart[t];
  float s1 = wave_sum(d.x);
  float s2 = wave_sum(d.y);
  float S = wave_sum(s);
  if (lane == 0) { r[0][wave] = s1; r[1][wave] = s2; r[2][wave] = S; }
  __syncthreads();
  if (t == 0) {
    double S1 = (double)r[0][0] + r[0][1] + r[0][2] + r[0][3];
    double S2 = (double)r[1][0] + r[1][1] + r[1][2] + r[1][3];
    double SS = (double)r[2][0] + r[2][1] + r[2][2] + r[2][3];
    double B = (double)NC;
    double inv_loss = S2 / (B * B) - 2.0 * S1 / B + (double)NC;
    double red_loss = (SS - S2) / (B * B);
    out[0] = (float)(inv_loss + (double)LAMBDA * red_loss);
  }
}

extern "C" void kernel_launch(void* const* d_in, const int* in_sizes, int n_in,
                              void* d_out, int out_size, void* d_ws, size_t ws_size,
                              hipStream_t stream) {
  const float* z = (const float*)d_in[0];
  const int* labels = (const int*)d_in[1];
  float* out = (float*)d_out;
  float* ws = (float*)d_ws;

  // ws layout (floats): [cn NC*FD][partials 2*NPB*FD*FD][dpart 512][spart 256]
  float* cn = ws;
  float* partials = ws + (size_t)NC * FD;
  float2* dpart = (float2*)(partials + (size_t)2 * NPB * FD * FD);
  float* spart = (float*)(dpart + 256);

  center_kernel<<<NC / CB, 256, 0, stream>>>(z, labels, cn, dpart);
  gram_kernel<<<2 * NPB, 256, 0, stream>>>(z, cn, partials);
  reduce_kernel<<<FD * FD / 64, 256, 0, stream>>>(partials, spart);
  final_kernel<<<1, 256, 0, stream>>>(dpart, spart, out);
}

// Round 5
// 75.422 us; speedup vs baseline: 3.9476x; 1.1034x over previous
//
#include <hip/hip_runtime.h>

#define NC 16384        // num classes == batch
#define FD 128          // feature dim
#define LAMBDA 0.005f
#define CB 16           // classes per center block (1024 blocks -> 4/CU)
#define CHUNK 128       // K rows per gram block
#define STAGE 64        // rows per LDS stage
#define NPB 128         // gram partial blocks per matrix (NC/CHUNK)
#define LISTCAP 256

__device__ __forceinline__ float wave_sum(float v) {
#pragma unroll
  for (int m = 32; m > 0; m >>= 1) v += __shfl_xor(v, m, 64);
  return v;
}

// --- 1. centers + diag: per-class mean + L2 normalize -> cn; also
//        s1/s2 diag partials for rows [b*CB, b*CB+CB) (plain store, no atomics)
__global__ __launch_bounds__(256) void center_kernel(
    const float* __restrict__ z, const int* __restrict__ labels,
    float* __restrict__ cn, float2* __restrict__ dpart) {
  __shared__ float sums[CB * FD];   // 8 KB
  __shared__ int list[LISTCAP];     // 1 KB
  __shared__ int counts[CB];
  __shared__ int nlist;
  __shared__ float red[8];
  int t = threadIdx.x, wave = t >> 6, lane = t & 63;
  int base = blockIdx.x * CB;

  for (int k = t; k < CB * FD; k += 256) sums[k] = 0.f;
  if (t < CB) counts[t] = 0;
  if (t == 0) nlist = 0;
  __syncthreads();

  // scan labels (64 KB, L2-resident across blocks)
#pragma unroll 4
  for (int k = 0; k < NC / 256; ++k) {
    int j = k * 256 + t;
    int lab = labels[j];
    unsigned loc = (unsigned)(lab - base);
    if (loc < CB) {
      int pos = atomicAdd(&nlist, 1);              // LDS atomic
      if (pos < LISTCAP) list[pos] = (j << 4) | (int)loc;
      atomicAdd(&counts[loc], 1);                  // LDS atomic
    }
  }
  __syncthreads();

  // accumulate: 8 independent 32-lane groups, fire-and-forget LDS f32 atomics
  int n = nlist > LISTCAP ? LISTCAP : nlist;
  int g = t >> 5;          // 0..7
  int sl = t & 31;         // 32 lanes x float4 = 128 dims
  for (int e = g; e < n; e += 8) {
    int ent = list[e];
    int loc = ent & (CB - 1);
    int i = ent >> 4;
    const float4 v = *(const float4*)&z[(size_t)i * FD + sl * 4];
    float* s = &sums[loc * FD + sl * 4];
    atomicAdd(s + 0, v.x);   // ds_add_f32, no return -> pipelines
    atomicAdd(s + 1, v.y);
    atomicAdd(s + 2, v.z);
    atomicAdd(s + 3, v.w);
  }
  __syncthreads();

  // divide, normalize, write cn; fused diag (z rows are contiguous here)
  float s1 = 0.f, s2 = 0.f;
#pragma unroll
  for (int j = 0; j < CB / 4; ++j) {
    int row = wave * (CB / 4) + j;
    int gr = base + row;
    int cnt = counts[row];
    float inv = cnt > 0 ? 1.0f / (float)cnt : 0.0f;
    float2 c = *(const float2*)&sums[row * FD + lane * 2];
    c.x *= inv; c.y *= inv;
    float sc = wave_sum(c.x * c.x + c.y * c.y);
    float ic = 1.0f / fmaxf(sqrtf(sc), 1e-12f);
    c.x *= ic; c.y *= ic;
    *(float2*)&cn[(size_t)gr * FD + lane * 2] = c;
    float2 a = *(const float2*)&z[(size_t)gr * FD + lane * 2];
    float na = wave_sum(a.x * a.x + a.y * a.y);
    float dd = wave_sum(a.x * c.x + a.y * c.y);
    float d = dd * (1.0f / fmaxf(sqrtf(na), 1e-12f));
    s1 += d; s2 += d * d;
  }
  if (lane == 0) { red[wave * 2] = s1; red[wave * 2 + 1] = s2; }
  __syncthreads();
  if (t == 0) {
    dpart[blockIdx.x] = make_float2(red[0] + red[2] + red[4] + red[6],
                                    red[1] + red[3] + red[5] + red[7]);
  }
}

// --- 2. gram partials: block b -> matrix m=b&1, K-chunk b>>1 (128 rows) ------
__global__ __launch_bounds__(256) void gram_kernel(
    const float* __restrict__ z, const float* __restrict__ cn,
    float* __restrict__ partials) {
  __shared__ float tile[STAGE * FD];  // 32 KB
  int t = threadIdx.x, wave = t >> 6, lane = t & 63;
  int b = blockIdx.x;
  int m = b & 1;
  int chunk = b >> 1;
  const float* A = m ? cn : z;
  int tx = t & 15, ty = t >> 4;

  float4 acc[8][2];
#pragma unroll
  for (int i = 0; i < 8; ++i) {
    acc[i][0] = make_float4(0.f, 0.f, 0.f, 0.f);
    acc[i][1] = make_float4(0.f, 0.f, 0.f, 0.f);
  }
  const float4* t4 = (const float4*)tile;

  for (int s = 0; s < CHUNK / STAGE; ++s) {
    {  // stage 64x128 floats, coalesced float4
      const float4* src = (const float4*)&A[(size_t)(chunk * CHUNK + s * STAGE) * FD];
      float4* dst = (float4*)tile;
#pragma unroll
      for (int k = 0; k < (STAGE * FD / 4) / 256; ++k)
        dst[k * 256 + t] = src[k * 256 + t];
    }
    __syncthreads();
    if (m == 0) {  // normalize z rows in LDS (16 rows per wave)
      float2* t2 = (float2*)tile;
#pragma unroll
      for (int j = 0; j < 16; ++j) {
        int row = wave * 16 + j;
        float2 v = t2[row * 64 + lane];
        float ss = wave_sum(v.x * v.x + v.y * v.y);
        float sc = 1.0f / fmaxf(sqrtf(ss), 1e-12f);
        v.x *= sc; v.y *= sc;
        t2[row * 64 + lane] = v;
      }
      __syncthreads();
    }
    // FMA loop with one-row register prefetch
    float4 a0 = t4[ty * 2], a1 = t4[ty * 2 + 1];
    float4 b0 = t4[tx * 2], b1 = t4[tx * 2 + 1];
    for (int r = 0; r < STAGE; ++r) {
      int rn = (r + 1) & (STAGE - 1);
      float4 na0 = t4[rn * 32 + ty * 2];
      float4 na1 = t4[rn * 32 + ty * 2 + 1];
      float4 nb0 = t4[rn * 32 + tx * 2];
      float4 nb1 = t4[rn * 32 + tx * 2 + 1];
      float av[8] = {a0.x, a0.y, a0.z, a0.w, a1.x, a1.y, a1.z, a1.w};
#pragma unroll
      for (int i = 0; i < 8; ++i) {
        float a = av[i];
        acc[i][0].x += a * b0.x;
        acc[i][0].y += a * b0.y;
        acc[i][0].z += a * b0.z;
        acc[i][0].w += a * b0.w;
        acc[i][1].x += a * b1.x;
        acc[i][1].y += a * b1.y;
        acc[i][1].z += a * b1.z;
        acc[i][1].w += a * b1.w;
      }
      a0 = na0; a1 = na1; b0 = nb0; b1 = nb1;
    }
    __syncthreads();
  }

  // plain coalesced partial store (no atomics)
  int d0 = ty * 8, e0 = tx * 8;
  float* P = &partials[(size_t)b * (FD * FD)];
#pragma unroll
  for (int i = 0; i < 8; ++i) {
    *(float4*)&P[(d0 + i) * FD + e0] = acc[i][0];
    *(float4*)&P[(d0 + i) * FD + e0 + 4] = acc[i][1];
  }
}

// --- 3. reduce partials -> per-block Frobenius partial (plain store) ---------
__global__ __launch_bounds__(256) void reduce_kernel(
    const float* __restrict__ partials, float* __restrict__ spart) {
  __shared__ float lz[4][64], lc[4][64];
  int t = threadIdx.x, wave = t >> 6, lane = t & 63;
  int e = blockIdx.x * 64 + lane;
  float sz = 0.f, sc = 0.f;
#pragma unroll 4
  for (int k = 0; k < NPB / 4; ++k) {
    int c = wave * (NPB / 4) + k;
    sz += partials[(size_t)(2 * c) * (FD * FD) + e];
    sc += partials[(size_t)(2 * c + 1) * (FD * FD) + e];
  }
  lz[wave][lane] = sz;
  lc[wave][lane] = sc;
  __syncthreads();
  if (wave == 0) {
    float tz = lz[0][lane] + lz[1][lane] + lz[2][lane] + lz[3][lane];
    float tc = lc[0][lane] + lc[1][lane] + lc[2][lane] + lc[3][lane];
    float S = wave_sum(tz * tc);
    if (lane == 0) spart[blockIdx.x] = S;
  }
}

// --- 4. final: sum 1024 dpart + 256 spart, compose loss ----------------------
__global__ __launch_bounds__(256) void final_kernel(
    const float2* __restrict__ dpart, const float* __restrict__ spart,
    float* __restrict__ out) {
  __shared__ float r[3][4];
  int t = threadIdx.x, wave = t >> 6, lane = t & 63;
  float a1 = 0.f, a2 = 0.f;
#pragma unroll
  for (int k = 0; k < 4; ++k) {
    float2 d = dpart[k * 256 + t];
    a1 += d.x; a2 += d.y;
  }
  float s = spart[t];
  float s1 = wave_sum(a1);
  float s2 = wave_sum(a2);
  float S = wave_sum(s);
  if (lane == 0) { r[0][wave] = s1; r[1][wave] = s2; r[2][wave] = S; }
  __syncthreads();
  if (t == 0) {
    double S1 = (double)r[0][0] + r[0][1] + r[0][2] + r[0][3];
    double S2 = (double)r[1][0] + r[1][1] + r[1][2] + r[1][3];
    double SS = (double)r[2][0] + r[2][1] + r[2][2] + r[2][3];
    double B = (double)NC;
    double inv_loss = S2 / (B * B) - 2.0 * S1 / B + (double)NC;
    double red_loss = (SS - S2) / (B * B);
    out[0] = (float)(inv_loss + (double)LAMBDA * red_loss);
  }
}

extern "C" void kernel_launch(void* const* d_in, const int* in_sizes, int n_in,
                              void* d_out, int out_size, void* d_ws, size_t ws_size,
                              hipStream_t stream) {
  const float* z = (const float*)d_in[0];
  const int* labels = (const int*)d_in[1];
  float* out = (float*)d_out;
  float* ws = (float*)d_ws;

  // ws layout (floats): [cn NC*FD][partials 2*NPB*FD*FD][dpart 2048][spart 256]
  float* cn = ws;
  float* partials = ws + (size_t)NC * FD;
  float2* dpart = (float2*)(partials + (size_t)2 * NPB * FD * FD);
  float* spart = (float*)(dpart + 1024);

  center_kernel<<<NC / CB, 256, 0, stream>>>(z, labels, cn, dpart);
  gram_kernel<<<2 * NPB, 256, 0, stream>>>(z, cn, partials);
  reduce_kernel<<<FD * FD / 64, 256, 0, stream>>>(partials, spart);
  final_kernel<<<1, 256, 0, stream>>>(dpart, spart, out);
}

// Round 6
// 56.101 us; speedup vs baseline: 5.3071x; 1.3444x over previous
//
#include <hip/hip_runtime.h>

#define NC 16384        // num classes == batch
#define FD 128          // feature dim
#define LAMBDA 0.005f
#define CHUNK 128       // K rows per gram block
#define STAGE 64        // rows per LDS stage
#define NPB 128         // gram partial blocks per matrix (NC/CHUNK)
#define SLOTCAP 64      // max samples tracked per class (Poisson(1): P(>64)~0)

__device__ __forceinline__ float wave_sum(float v) {
#pragma unroll
  for (int m = 32; m > 0; m >>= 1) v += __shfl_xor(v, m, 64);
  return v;
}

// --- 1. scatter: slot[lab][k] = sample index (16K int atomics) ---------------
__global__ __launch_bounds__(256) void scatter_kernel(
    const int* __restrict__ labels, int* __restrict__ cnt, int* __restrict__ slot) {
  int i = blockIdx.x * 256 + threadIdx.x;
  int lab = labels[i];
  int p = atomicAdd(&cnt[lab], 1);
  if (p < SLOTCAP) slot[(size_t)lab * SLOTCAP + p] = i;
}

// --- 2. centers + diag: one wave per class -----------------------------------
__global__ __launch_bounds__(256) void center_kernel(
    const float* __restrict__ z, const int* __restrict__ cnt,
    const int* __restrict__ slot, float* __restrict__ cn,
    float2* __restrict__ dpart) {
  __shared__ float red[8];
  int t = threadIdx.x, wave = t >> 6, lane = t & 63;
  int c = blockIdx.x * 4 + wave;

  int n = cnt[c];
  if (n > SLOTCAP) n = SLOTCAP;
  float2 s = make_float2(0.f, 0.f);
  for (int k = 0; k < n; ++k) {
    int i = slot[(size_t)c * SLOTCAP + k];
    float2 v = *(const float2*)&z[(size_t)i * FD + lane * 2];
    s.x += v.x; s.y += v.y;
  }
  float inv = n > 0 ? 1.0f / (float)n : 0.0f;
  s.x *= inv; s.y *= inv;
  float sc = wave_sum(s.x * s.x + s.y * s.y);
  float ic = 1.0f / fmaxf(sqrtf(sc), 1e-12f);
  s.x *= ic; s.y *= ic;
  *(float2*)&cn[(size_t)c * FD + lane * 2] = s;

  // diag: d_c = (z_c / ||z_c||) . cn_c
  float2 a = *(const float2*)&z[(size_t)c * FD + lane * 2];
  float na = wave_sum(a.x * a.x + a.y * a.y);
  float dd = wave_sum(a.x * s.x + a.y * s.y);
  float d = dd * (1.0f / fmaxf(sqrtf(na), 1e-12f));
  if (lane == 0) { red[wave * 2] = d; red[wave * 2 + 1] = d * d; }
  __syncthreads();
  if (t == 0) {
    dpart[blockIdx.x] = make_float2(red[0] + red[2] + red[4] + red[6],
                                    red[1] + red[3] + red[5] + red[7]);
  }
}

// --- 3. gram partials: block b -> matrix m=b&1, K-chunk b>>1 (128 rows) ------
__global__ __launch_bounds__(256) void gram_kernel(
    const float* __restrict__ z, const float* __restrict__ cn,
    float* __restrict__ partials) {
  __shared__ float tile[STAGE * FD];  // 32 KB
  int t = threadIdx.x, wave = t >> 6, lane = t & 63;
  int b = blockIdx.x;
  int m = b & 1;
  int chunk = b >> 1;
  const float* A = m ? cn : z;
  int tx = t & 15, ty = t >> 4;

  float4 acc[8][2];
#pragma unroll
  for (int i = 0; i < 8; ++i) {
    acc[i][0] = make_float4(0.f, 0.f, 0.f, 0.f);
    acc[i][1] = make_float4(0.f, 0.f, 0.f, 0.f);
  }
  const float4* t4 = (const float4*)tile;

  for (int s = 0; s < CHUNK / STAGE; ++s) {
    {  // stage 64x128 floats, coalesced float4
      const float4* src = (const float4*)&A[(size_t)(chunk * CHUNK + s * STAGE) * FD];
      float4* dst = (float4*)tile;
#pragma unroll
      for (int k = 0; k < (STAGE * FD / 4) / 256; ++k)
        dst[k * 256 + t] = src[k * 256 + t];
    }
    __syncthreads();
    if (m == 0) {  // normalize z rows in LDS (16 rows per wave)
      float2* t2 = (float2*)tile;
#pragma unroll
      for (int j = 0; j < 16; ++j) {
        int row = wave * 16 + j;
        float2 v = t2[row * 64 + lane];
        float ss = wave_sum(v.x * v.x + v.y * v.y);
        float sc = 1.0f / fmaxf(sqrtf(ss), 1e-12f);
        v.x *= sc; v.y *= sc;
        t2[row * 64 + lane] = v;
      }
      __syncthreads();
    }
    // FMA loop with one-row register prefetch
    float4 a0 = t4[ty * 2], a1 = t4[ty * 2 + 1];
    float4 b0 = t4[tx * 2], b1 = t4[tx * 2 + 1];
    for (int r = 0; r < STAGE; ++r) {
      int rn = (r + 1) & (STAGE - 1);
      float4 na0 = t4[rn * 32 + ty * 2];
      float4 na1 = t4[rn * 32 + ty * 2 + 1];
      float4 nb0 = t4[rn * 32 + tx * 2];
      float4 nb1 = t4[rn * 32 + tx * 2 + 1];
      float av[8] = {a0.x, a0.y, a0.z, a0.w, a1.x, a1.y, a1.z, a1.w};
#pragma unroll
      for (int i = 0; i < 8; ++i) {
        float a = av[i];
        acc[i][0].x += a * b0.x;
        acc[i][0].y += a * b0.y;
        acc[i][0].z += a * b0.z;
        acc[i][0].w += a * b0.w;
        acc[i][1].x += a * b1.x;
        acc[i][1].y += a * b1.y;
        acc[i][1].z += a * b1.z;
        acc[i][1].w += a * b1.w;
      }
      a0 = na0; a1 = na1; b0 = nb0; b1 = nb1;
    }
    __syncthreads();
  }

  // plain coalesced partial store (no atomics)
  int d0 = ty * 8, e0 = tx * 8;
  float* P = &partials[(size_t)b * (FD * FD)];
#pragma unroll
  for (int i = 0; i < 8; ++i) {
    *(float4*)&P[(d0 + i) * FD + e0] = acc[i][0];
    *(float4*)&P[(d0 + i) * FD + e0 + 4] = acc[i][1];
  }
}

// --- 4. reduce partials -> per-block Frobenius partial (plain store) ---------
__global__ __launch_bounds__(256) void reduce_kernel(
    const float* __restrict__ partials, float* __restrict__ spart) {
  __shared__ float lz[4][64], lc[4][64];
  int t = threadIdx.x, wave = t >> 6, lane = t & 63;
  int e = blockIdx.x * 64 + lane;
  float sz = 0.f, sc = 0.f;
#pragma unroll 4
  for (int k = 0; k < NPB / 4; ++k) {
    int c = wave * (NPB / 4) + k;
    sz += partials[(size_t)(2 * c) * (FD * FD) + e];
    sc += partials[(size_t)(2 * c + 1) * (FD * FD) + e];
  }
  lz[wave][lane] = sz;
  lc[wave][lane] = sc;
  __syncthreads();
  if (wave == 0) {
    float tz = lz[0][lane] + lz[1][lane] + lz[2][lane] + lz[3][lane];
    float tc = lc[0][lane] + lc[1][lane] + lc[2][lane] + lc[3][lane];
    float S = wave_sum(tz * tc);
    if (lane == 0) spart[blockIdx.x] = S;
  }
}

// --- 5. final: sum 4096 dpart + 256 spart, compose loss ----------------------
__global__ __launch_bounds__(256) void final_kernel(
    const float2* __restrict__ dpart, const float* __restrict__ spart,
    float* __restrict__ out) {
  __shared__ float r[3][4];
  int t = threadIdx.x, wave = t >> 6, lane = t & 63;
  float a1 = 0.f, a2 = 0.f;
#pragma unroll
  for (int k = 0; k < 16; ++k) {
    float2 d = dpart[k * 256 + t];
    a1 += d.x; a2 += d.y;
  }
  float s = spart[t];
  float s1 = wave_sum(a1);
  float s2 = wave_sum(a2);
  float S = wave_sum(s);
  if (lane == 0) { r[0][wave] = s1; r[1][wave] = s2; r[2][wave] = S; }
  __syncthreads();
  if (t == 0) {
    double S1 = (double)r[0][0] + r[0][1] + r[0][2] + r[0][3];
    double S2 = (double)r[1][0] + r[1][1] + r[1][2] + r[1][3];
    double SS = (double)r[2][0] + r[2][1] + r[2][2] + r[2][3];
    double B = (double)NC;
    double inv_loss = S2 / (B * B) - 2.0 * S1 / B + (double)NC;
    double red_loss = (SS - S2) / (B * B);
    out[0] = (float)(inv_loss + (double)LAMBDA * red_loss);
  }
}

extern "C" void kernel_launch(void* const* d_in, const int* in_sizes, int n_in,
                              void* d_out, int out_size, void* d_ws, size_t ws_size,
                              hipStream_t stream) {
  const float* z = (const float*)d_in[0];
  const int* labels = (const int*)d_in[1];
  float* out = (float*)d_out;
  float* ws = (float*)d_ws;

  // ws layout (floats):
  // [cn NC*FD][partials 2*NPB*FD*FD][dpart 2*4096][spart 256][cnt NC][slot NC*SLOTCAP]
  float* cn = ws;
  float* partials = ws + (size_t)NC * FD;
  float2* dpart = (float2*)(partials + (size_t)2 * NPB * FD * FD);
  float* spart = (float*)(dpart + 4096);
  int* cnt = (int*)(spart + 256);
  int* slot = cnt + NC;

  hipMemsetAsync(cnt, 0, NC * sizeof(int), stream);
  scatter_kernel<<<NC / 256, 256, 0, stream>>>(labels, cnt, slot);
  center_kernel<<<NC / 4, 256, 0, stream>>>(z, cnt, slot, cn, dpart);
  gram_kernel<<<2 * NPB, 256, 0, stream>>>(z, cn, partials);
  reduce_kernel<<<FD * FD / 64, 256, 0, stream>>>(partials, spart);
  final_kernel<<<1, 256, 0, stream>>>(dpart, spart, out);
}

// Round 7
// 53.515 us; speedup vs baseline: 5.5636x; 1.0483x over previous
//
#include <hip/hip_runtime.h>

#define NC 16384        // num classes == batch
#define FD 128          // feature dim
#define LAMBDA 0.005f
#define CHUNK 64        // K rows per gram block (one LDS stage)
#define STAGE 64        // rows per LDS stage
#define NPB (NC / CHUNK)  // 256 gram partial blocks per matrix
#define SLOTCAP 64      // max samples tracked per class (Poisson(1): P(>64)~0)

__device__ __forceinline__ float wave_sum(float v) {
#pragma unroll
  for (int m = 32; m > 0; m >>= 1) v += __shfl_xor(v, m, 64);
  return v;
}

// --- 0. zero cnt (replaces hipMemsetAsync's 40us blit) -----------------------
__global__ __launch_bounds__(256) void zero_kernel(int4* __restrict__ cnt4) {
  cnt4[blockIdx.x * 256 + threadIdx.x] = make_int4(0, 0, 0, 0);
}

// --- 1. scatter: slot[lab][k] = sample index (16K int atomics) ---------------
__global__ __launch_bounds__(256) void scatter_kernel(
    const int* __restrict__ labels, int* __restrict__ cnt, int* __restrict__ slot) {
  int i = blockIdx.x * 256 + threadIdx.x;
  int lab = labels[i];
  int p = atomicAdd(&cnt[lab], 1);
  if (p < SLOTCAP) slot[(size_t)lab * SLOTCAP + p] = i;
}

// --- 2. centers + diag: one wave per class -----------------------------------
__global__ __launch_bounds__(256) void center_kernel(
    const float* __restrict__ z, const int* __restrict__ cnt,
    const int* __restrict__ slot, float* __restrict__ cn,
    float2* __restrict__ dpart) {
  __shared__ float red[8];
  int t = threadIdx.x, wave = t >> 6, lane = t & 63;
  int c = blockIdx.x * 4 + wave;

  int n = cnt[c];
  if (n > SLOTCAP) n = SLOTCAP;
  float2 s = make_float2(0.f, 0.f);
  for (int k = 0; k < n; ++k) {
    int i = slot[(size_t)c * SLOTCAP + k];
    float2 v = *(const float2*)&z[(size_t)i * FD + lane * 2];
    s.x += v.x; s.y += v.y;
  }
  float inv = n > 0 ? 1.0f / (float)n : 0.0f;
  s.x *= inv; s.y *= inv;
  float sc = wave_sum(s.x * s.x + s.y * s.y);
  float ic = 1.0f / fmaxf(sqrtf(sc), 1e-12f);
  s.x *= ic; s.y *= ic;
  *(float2*)&cn[(size_t)c * FD + lane * 2] = s;

  // diag: d_c = (z_c / ||z_c||) . cn_c
  float2 a = *(const float2*)&z[(size_t)c * FD + lane * 2];
  float na = wave_sum(a.x * a.x + a.y * a.y);
  float dd = wave_sum(a.x * s.x + a.y * s.y);
  float d = dd * (1.0f / fmaxf(sqrtf(na), 1e-12f));
  if (lane == 0) { red[wave * 2] = d; red[wave * 2 + 1] = d * d; }
  __syncthreads();
  if (t == 0) {
    dpart[blockIdx.x] = make_float2(red[0] + red[2] + red[4] + red[6],
                                    red[1] + red[3] + red[5] + red[7]);
  }
}

// --- 3. gram partials: block b -> matrix m=b&1, K-chunk b>>1 (64 rows) -------
__global__ __launch_bounds__(256) void gram_kernel(
    const float* __restrict__ z, const float* __restrict__ cn,
    float* __restrict__ partials) {
  __shared__ float tile[STAGE * FD];  // 32 KB
  int t = threadIdx.x, wave = t >> 6, lane = t & 63;
  int b = blockIdx.x;
  int m = b & 1;
  int chunk = b >> 1;
  const float* A = m ? cn : z;
  int tx = t & 15, ty = t >> 4;

  float4 acc[8][2];
#pragma unroll
  for (int i = 0; i < 8; ++i) {
    acc[i][0] = make_float4(0.f, 0.f, 0.f, 0.f);
    acc[i][1] = make_float4(0.f, 0.f, 0.f, 0.f);
  }
  const float4* t4 = (const float4*)tile;

  {  // stage 64x128 floats, coalesced float4
    const float4* src = (const float4*)&A[(size_t)chunk * CHUNK * FD];
    float4* dst = (float4*)tile;
#pragma unroll
    for (int k = 0; k < (STAGE * FD / 4) / 256; ++k)
      dst[k * 256 + t] = src[k * 256 + t];
  }
  __syncthreads();
  if (m == 0) {  // normalize z rows in LDS (16 rows per wave)
    float2* t2 = (float2*)tile;
#pragma unroll
    for (int j = 0; j < 16; ++j) {
      int row = wave * 16 + j;
      float2 v = t2[row * 64 + lane];
      float ss = wave_sum(v.x * v.x + v.y * v.y);
      float sc = 1.0f / fmaxf(sqrtf(ss), 1e-12f);
      v.x *= sc; v.y *= sc;
      t2[row * 64 + lane] = v;
    }
    __syncthreads();
  }
  // FMA loop with one-row register prefetch
  float4 a0 = t4[ty * 2], a1 = t4[ty * 2 + 1];
  float4 b0 = t4[tx * 2], b1 = t4[tx * 2 + 1];
  for (int r = 0; r < STAGE; ++r) {
    int rn = (r + 1) & (STAGE - 1);
    float4 na0 = t4[rn * 32 + ty * 2];
    float4 na1 = t4[rn * 32 + ty * 2 + 1];
    float4 nb0 = t4[rn * 32 + tx * 2];
    float4 nb1 = t4[rn * 32 + tx * 2 + 1];
    float av[8] = {a0.x, a0.y, a0.z, a0.w, a1.x, a1.y, a1.z, a1.w};
#pragma unroll
    for (int i = 0; i < 8; ++i) {
      float a = av[i];
      acc[i][0].x += a * b0.x;
      acc[i][0].y += a * b0.y;
      acc[i][0].z += a * b0.z;
      acc[i][0].w += a * b0.w;
      acc[i][1].x += a * b1.x;
      acc[i][1].y += a * b1.y;
      acc[i][1].z += a * b1.z;
      acc[i][1].w += a * b1.w;
    }
    a0 = na0; a1 = na1; b0 = nb0; b1 = nb1;
  }

  // plain coalesced partial store (no atomics)
  int d0 = ty * 8, e0 = tx * 8;
  float* P = &partials[(size_t)b * (FD * FD)];
#pragma unroll
  for (int i = 0; i < 8; ++i) {
    *(float4*)&P[(d0 + i) * FD + e0] = acc[i][0];
    *(float4*)&P[(d0 + i) * FD + e0 + 4] = acc[i][1];
  }
}

// --- 4. reduce partials -> per-block Frobenius partial (plain store) ---------
__global__ __launch_bounds__(256) void reduce_kernel(
    const float* __restrict__ partials, float* __restrict__ spart) {
  __shared__ float lz[4][64], lc[4][64];
  int t = threadIdx.x, wave = t >> 6, lane = t & 63;
  int e = blockIdx.x * 64 + lane;
  float sz = 0.f, sc = 0.f;
#pragma unroll 4
  for (int k = 0; k < NPB / 4; ++k) {
    int c = wave * (NPB / 4) + k;
    sz += partials[(size_t)(2 * c) * (FD * FD) + e];
    sc += partials[(size_t)(2 * c + 1) * (FD * FD) + e];
  }
  lz[wave][lane] = sz;
  lc[wave][lane] = sc;
  __syncthreads();
  if (wave == 0) {
    float tz = lz[0][lane] + lz[1][lane] + lz[2][lane] + lz[3][lane];
    float tc = lc[0][lane] + lc[1][lane] + lc[2][lane] + lc[3][lane];
    float S = wave_sum(tz * tc);
    if (lane == 0) spart[blockIdx.x] = S;
  }
}

// --- 5. final: sum 4096 dpart + 256 spart, compose loss ----------------------
__global__ __launch_bounds__(256) void final_kernel(
    const float2* __restrict__ dpart, const float* __restrict__ spart,
    float* __restrict__ out) {
  __shared__ float r[3][4];
  int t = threadIdx.x, wave = t >> 6, lane = t & 63;
  float a1 = 0.f, a2 = 0.f;
#pragma unroll
  for (int k = 0; k < 16; ++k) {
    float2 d = dpart[k * 256 + t];
    a1 += d.x; a2 += d.y;
  }
  float s = spart[t];
  float s1 = wave_sum(a1);
  float s2 = wave_sum(a2);
  float S = wave_sum(s);
  if (lane == 0) { r[0][wave] = s1; r[1][wave] = s2; r[2][wave] = S; }
  __syncthreads();
  if (t == 0) {
    double S1 = (double)r[0][0] + r[0][1] + r[0][2] + r[0][3];
    double S2 = (double)r[1][0] + r[1][1] + r[1][2] + r[1][3];
    double SS = (double)r[2][0] + r[2][1] + r[2][2] + r[2][3];
    double B = (double)NC;
    double inv_loss = S2 / (B * B) - 2.0 * S1 / B + (double)NC;
    double red_loss = (SS - S2) / (B * B);
    out[0] = (float)(inv_loss + (double)LAMBDA * red_loss);
  }
}

extern "C" void kernel_launch(void* const* d_in, const int* in_sizes, int n_in,
                              void* d_out, int out_size, void* d_ws, size_t ws_size,
                              hipStream_t stream) {
  const float* z = (const float*)d_in[0];
  const int* labels = (const int*)d_in[1];
  float* out = (float*)d_out;
  float* ws = (float*)d_ws;

  // ws layout (floats):
  // [cn NC*FD][partials 2*NPB*FD*FD][dpart 2*4096][spart 256][cnt NC][slot NC*SLOTCAP]
  float* cn = ws;
  float* partials = ws + (size_t)NC * FD;
  float2* dpart = (float2*)(partials + (size_t)2 * NPB * FD * FD);
  float* spart = (float*)(dpart + 4096);
  int* cnt = (int*)(spart + 256);
  int* slot = cnt + NC;

  zero_kernel<<<NC / 1024, 256, 0, stream>>>((int4*)cnt);
  scatter_kernel<<<NC / 256, 256, 0, stream>>>(labels, cnt, slot);
  center_kernel<<<NC / 4, 256, 0, stream>>>(z, cnt, slot, cn, dpart);
  gram_kernel<<<2 * NPB, 256, 0, stream>>>(z, cn, partials);
  reduce_kernel<<<FD * FD / 64, 256, 0, stream>>>(partials, spart);
  final_kernel<<<1, 256, 0, stream>>>(dpart, spart, out);
}